// Round 1
// baseline (523.683 us; speedup 1.0000x reference)
//
#include <hip/hip_runtime.h>

#define SLEN 2048
#define NHEADS 16
#define HDIM 128

typedef __attribute__((ext_vector_type(8))) short bf16x8;
typedef __attribute__((ext_vector_type(4))) float f32x4;

__device__ __forceinline__ unsigned short f2bf(float f) {
  union { float f; unsigned u; } v; v.f = f;
  unsigned r = v.u + 0x7FFFu + ((v.u >> 16) & 1u);
  return (unsigned short)(r >> 16);
}

__device__ __forceinline__ void gload16(const void* g, void* l) {
  __builtin_amdgcn_global_load_lds(
      (const __attribute__((address_space(1))) unsigned int*)g,
      (__attribute__((address_space(3))) unsigned int*)l, 16, 0, 0);
}

// ---------------- f32 -> bf16 conversion (8 elems/thread) ----------------
__global__ __launch_bounds__(256) void cvt_f32_bf16(const float* __restrict__ in,
                                                    unsigned short* __restrict__ out,
                                                    int n8) {
  int i = blockIdx.x * 256 + threadIdx.x;
  if (i >= n8) return;
  const float4* p = reinterpret_cast<const float4*>(in) + (size_t)i * 2;
  float4 a = p[0], b = p[1];
  uint4 o;
  o.x = (unsigned)f2bf(a.x) | ((unsigned)f2bf(a.y) << 16);
  o.y = (unsigned)f2bf(a.z) | ((unsigned)f2bf(a.w) << 16);
  o.z = (unsigned)f2bf(b.x) | ((unsigned)f2bf(b.y) << 16);
  o.w = (unsigned)f2bf(b.z) | ((unsigned)f2bf(b.w) << 16);
  reinterpret_cast<uint4*>(out)[i] = o;
}

// ---------------- C = A[M,K] * B[N,K]^T, bf16 in, f32 acc ----------------
// m97 structure: 128x128 tile, BK=32, 4 waves (2x2 of 64x64), global_load_lds.
template <bool OUT_F32>
__global__ __launch_bounds__(256) void gemm_bt(const unsigned short* __restrict__ A,
                                               const unsigned short* __restrict__ B,
                                               void* __restrict__ Cv,
                                               int M, int N, int K) {
  __shared__ unsigned short As[128 * 32];
  __shared__ unsigned short Bs[128 * 32];
  const int tid = threadIdx.x;
  const int lane = tid & 63, wid = tid >> 6;
  const int g = lane >> 4, q = lane & 15;
  const int nbx = N >> 7;
  const int bx = blockIdx.x % nbx, by = blockIdx.x / nbx;
  const int tM = by << 7, tN = bx << 7;
  const int wm = (wid >> 1) * 64, wn = (wid & 1) * 64;

  f32x4 acc[4][4] = {};

  // staging coords: linear byte offset o = tid*16 (+4096 for round 1)
  const int o0 = tid * 16;
  const int r0 = o0 >> 6, c0 = (o0 & 63) >> 1;  // row, elem col in [0,32)
  const int r1 = r0 + 64;
  const unsigned short* gA0 = A + (size_t)(tM + r0) * K + c0;
  const unsigned short* gA1 = A + (size_t)(tM + r1) * K + c0;
  const unsigned short* gB0 = B + (size_t)(tN + r0) * K + c0;
  const unsigned short* gB1 = B + (size_t)(tN + r1) * K + c0;
  char* lA = (char*)As;
  char* lB = (char*)Bs;
  const int wo = wid * 1024;

  for (int kt = 0; kt < K; kt += 32) {
    gload16(gA0, lA + wo);
    gload16(gA1, lA + 4096 + wo);
    gload16(gB0, lB + wo);
    gload16(gB1, lB + 4096 + wo);
    gA0 += 32; gA1 += 32; gB0 += 32; gB1 += 32;
    __syncthreads();
    bf16x8 af[4], bfr[4];
#pragma unroll
    for (int i = 0; i < 4; ++i)
      af[i] = *(const bf16x8*)&As[(wm + i * 16 + q) * 32 + g * 8];
#pragma unroll
    for (int j = 0; j < 4; ++j)
      bfr[j] = *(const bf16x8*)&Bs[(wn + j * 16 + q) * 32 + g * 8];
#pragma unroll
    for (int i = 0; i < 4; ++i)
#pragma unroll
      for (int j = 0; j < 4; ++j)
        acc[i][j] = __builtin_amdgcn_mfma_f32_16x16x32_bf16(af[i], bfr[j], acc[i][j], 0, 0, 0);
    __syncthreads();
  }

  // epilogue: D row = g*4+r, col = q (m89-verified layout)
  if constexpr (OUT_F32) {
    float* C = (float*)Cv;
#pragma unroll
    for (int i = 0; i < 4; ++i)
#pragma unroll
      for (int j = 0; j < 4; ++j)
#pragma unroll
        for (int r = 0; r < 4; ++r)
          C[(size_t)(tM + wm + i * 16 + g * 4 + r) * N + (tN + wn + j * 16 + q)] =
              acc[i][j][r];
  } else {
    unsigned short* C = (unsigned short*)Cv;
#pragma unroll
    for (int i = 0; i < 4; ++i)
#pragma unroll
      for (int j = 0; j < 4; ++j)
#pragma unroll
        for (int r = 0; r < 4; ++r)
          C[(size_t)(tM + wm + i * 16 + g * 4 + r) * N + (tN + wn + j * 16 + q)] =
              f2bf(acc[i][j][r]);
  }
}

// ---------------- causal flash attention, 32 (b,h) pairs ----------------
// block: 256 thr = 4 waves; each wave owns 16 q-rows; Q-tile 64, KV-tile 64.
// Swapped QK^T: S^T = mfma(K, Q) so K/Q frags load 16B-contiguous from global.
__global__ __launch_bounds__(256) void mla_attn(const unsigned short* __restrict__ QP,
                                                const unsigned short* __restrict__ KV,
                                                unsigned short* __restrict__ AO) {
  __shared__ unsigned short Vt[128 * 72];   // V^T: [d][kv], stride 72 (16B-aligned reads)
  __shared__ unsigned short Pl[4][16 * 72]; // per-wave P: [q][kv], stride 72

  const int tid = threadIdx.x, lane = tid & 63, w = tid >> 6;
  const int g = lane >> 4, q = lane & 15;
  const int nqt = SLEN / 64;
  const int qt = blockIdx.x % nqt;
  const int bh = blockIdx.x / nqt;
  const int h = bh % NHEADS, b = bh / NHEADS;
  const int qrow0 = qt * 64;
  const int myq = qrow0 + w * 16 + q;  // this lane's absolute q row

  const unsigned short* Qb = QP + (size_t)(b * SLEN) * 2048 + h * HDIM;
  const unsigned short* Kb = KV + (size_t)(b * SLEN) * 4096 + h * HDIM;
  const unsigned short* Vb = Kb + 2048;

  // hoist Q B-frags: col = q row (lane&15), k = d = c*32 + g*8 + j
  bf16x8 qf[4];
#pragma unroll
  for (int c = 0; c < 4; ++c)
    qf[c] = *(const bf16x8*)(Qb + (size_t)myq * 2048 + c * 32 + g * 8);

  float m = -1e30f, l = 0.f;
  f32x4 o[8] = {};
  const float sc_f = 0.08838834764831845f;  // 1/sqrt(128)

  for (int kt = 0; kt <= qt; ++kt) {
    const int kvb = kt * 64;
    __syncthreads();  // protect Vt against previous iteration's readers
    // V^T staging: lane covers kv row = lane, d chunk = w*8 + rr*32.
    // u16 writes land 2 lanes/bank on the SAME dword -> ~conflict-free.
#pragma unroll
    for (int rr = 0; rr < 4; ++rr) {
      const int dc = w * 8 + rr * 32;
      bf16x8 v = *(const bf16x8*)(Vb + (size_t)(kvb + lane) * 4096 + dc);
#pragma unroll
      for (int j = 0; j < 8; ++j)
        Vt[(dc + j) * 72 + lane] = (unsigned short)v[j];
    }
    __syncthreads();

    // S^T = K * Q^T : A-frag row = kv (lane&15), direct from global
    f32x4 s4[4];
#pragma unroll
    for (int mf = 0; mf < 4; ++mf) {
      s4[mf] = (f32x4){0.f, 0.f, 0.f, 0.f};
      const unsigned short* kp = Kb + (size_t)(kvb + mf * 16 + q) * 4096 + g * 8;
#pragma unroll
      for (int c = 0; c < 4; ++c) {
        bf16x8 af = *(const bf16x8*)(kp + c * 32);
        s4[mf] = __builtin_amdgcn_mfma_f32_16x16x32_bf16(af, qf[c], s4[mf], 0, 0, 0);
      }
    }

    // lane holds 16 scores for q-row myq: kv = kvb + mf*16 + g*4 + r
    float p[16], tmax = -1e30f;
#pragma unroll
    for (int mf = 0; mf < 4; ++mf)
#pragma unroll
      for (int r = 0; r < 4; ++r) {
        const int kv = kvb + mf * 16 + g * 4 + r;
        float s = (kv <= myq) ? s4[mf][r] * sc_f : -1e30f;
        p[mf * 4 + r] = s;
        tmax = fmaxf(tmax, s);
      }
    tmax = fmaxf(tmax, __shfl_xor(tmax, 16));
    tmax = fmaxf(tmax, __shfl_xor(tmax, 32));
    const float mnew = fmaxf(m, tmax);
    const float resc = __expf(m - mnew);
    m = mnew;
    float ts = 0.f;
#pragma unroll
    for (int i = 0; i < 16; ++i) { p[i] = __expf(p[i] - mnew); ts += p[i]; }
    ts += __shfl_xor(ts, 16);
    ts += __shfl_xor(ts, 32);
    l = l * resc + ts;

    // rescale O: O rows are q-local = g*4+r; fetch that row's factor from lane (g*4+r)
    float rs[4];
#pragma unroll
    for (int r = 0; r < 4; ++r) rs[r] = __shfl(resc, g * 4 + r);
#pragma unroll
    for (int nf = 0; nf < 8; ++nf)
#pragma unroll
      for (int r = 0; r < 4; ++r) o[nf][r] *= rs[r];

    // P -> LDS (bf16) in [q][kv] layout; lane owns kv runs of 4
    unsigned short* myP = &Pl[w][0];
#pragma unroll
    for (int mf = 0; mf < 4; ++mf) {
      unsigned lo = (unsigned)f2bf(p[mf * 4 + 0]) | ((unsigned)f2bf(p[mf * 4 + 1]) << 16);
      unsigned hi = (unsigned)f2bf(p[mf * 4 + 2]) | ((unsigned)f2bf(p[mf * 4 + 3]) << 16);
      *(uint2*)&myP[q * 72 + mf * 16 + g * 4] = make_uint2(lo, hi);
    }

    // PV: O[16q][128d] += P[16q][64kv] * V[64kv][128d]
#pragma unroll
    for (int t = 0; t < 2; ++t) {
      bf16x8 pa = *(const bf16x8*)&myP[q * 72 + t * 32 + g * 8];
#pragma unroll
      for (int nf = 0; nf < 8; ++nf) {
        bf16x8 vbf = *(const bf16x8*)&Vt[(nf * 16 + q) * 72 + t * 32 + g * 8];
        o[nf] = __builtin_amdgcn_mfma_f32_16x16x32_bf16(pa, vbf, o[nf], 0, 0, 0);
      }
    }
  }

  const float inv = 1.0f / l;
  float li[4];
#pragma unroll
  for (int r = 0; r < 4; ++r) li[r] = __shfl(inv, g * 4 + r);
  unsigned short* aop = AO + (size_t)(b * SLEN + qrow0 + w * 16) * 2048 + h * HDIM;
#pragma unroll
  for (int nf = 0; nf < 8; ++nf)
#pragma unroll
    for (int r = 0; r < 4; ++r)
      aop[(size_t)(g * 4 + r) * 2048 + nf * 16 + q] = f2bf(o[nf][r] * li[r]);
}

extern "C" void kernel_launch(void* const* d_in, const int* in_sizes, int n_in,
                              void* d_out, int out_size, void* d_ws, size_t ws_size,
                              hipStream_t stream) {
  const float* q    = (const float*)d_in[0];  // [2,2048,2048]
  const float* lat  = (const float*)d_in[1];  // [2,2048,512]
  const float* Wq   = (const float*)d_in[2];  // [2048,2048]
  const float* Wkv  = (const float*)d_in[3];  // [4096,512]
  const float* Wout = (const float*)d_in[4];  // [2048,2048]

  char* ws = (char*)d_ws;
  unsigned short* qbf   = (unsigned short*)(ws);             // 16 MiB [4096,2048]
  unsigned short* aobf  = (unsigned short*)(ws);             // reuses qbf (dead after GEMM1)
  unsigned short* Wqbf  = (unsigned short*)(ws + 16777216);  // 8 MiB
  unsigned short* latbf = (unsigned short*)(ws + 25165824);  // 4 MiB
  unsigned short* Wkvbf = (unsigned short*)(ws + 29360128);  // 4 MiB
  unsigned short* Wobf  = (unsigned short*)(ws + 33554432);  // 8 MiB
  unsigned short* qpbf  = (unsigned short*)(ws + 41943040);  // 16 MiB [4096,2048]
  unsigned short* kvbf  = (unsigned short*)(ws + 58720256);  // 32 MiB [4096,4096]
  // total 92274688 B

  cvt_f32_bf16<<<4096, 256, 0, stream>>>(q, qbf, 1048576);
  cvt_f32_bf16<<<2048, 256, 0, stream>>>(Wq, Wqbf, 524288);
  cvt_f32_bf16<<<1024, 256, 0, stream>>>(lat, latbf, 262144);
  cvt_f32_bf16<<<1024, 256, 0, stream>>>(Wkv, Wkvbf, 262144);
  cvt_f32_bf16<<<2048, 256, 0, stream>>>(Wout, Wobf, 524288);

  // qp = q * Wq^T   [4096,2048] = [4096,2048]x[2048,2048]^T
  gemm_bt<false><<<512, 256, 0, stream>>>(qbf, Wqbf, qpbf, 4096, 2048, 2048);
  // kv = latent * Wkv^T  [4096,4096] = [4096,512]x[4096,512]^T
  gemm_bt<false><<<1024, 256, 0, stream>>>(latbf, Wkvbf, kvbf, 4096, 4096, 512);
  // attention: grid = B*NH*(S/64) = 1024
  mla_attn<<<1024, 256, 0, stream>>>(qpbf, kvbf, aobf);
  // out = ao * Wout^T -> f32
  gemm_bt<true><<<512, 256, 0, stream>>>(aobf, Wobf, (float*)d_out, 4096, 2048, 2048);
}

// Round 2
// 256.436 us; speedup vs baseline: 2.0422x; 2.0422x over previous
//
#include <hip/hip_runtime.h>

#define SLEN 2048
#define NHEADS 16
#define HDIM 128

typedef __attribute__((ext_vector_type(8))) short bf16x8;
typedef __attribute__((ext_vector_type(4))) float f32x4;

__device__ __forceinline__ unsigned short f2bf(float f) {
  union { float f; unsigned u; } v; v.f = f;
  unsigned r = v.u + 0x7FFFu + ((v.u >> 16) & 1u);
  return (unsigned short)(r >> 16);
}

__device__ __forceinline__ void gload16(const void* g, void* l) {
  __builtin_amdgcn_global_load_lds(
      (const __attribute__((address_space(1))) unsigned int*)g,
      (__attribute__((address_space(3))) unsigned int*)l, 16, 0, 0);
}

// ---------------- f32 -> bf16 conversion (8 elems/thread) ----------------
__global__ __launch_bounds__(256) void cvt_f32_bf16(const float* __restrict__ in,
                                                    unsigned short* __restrict__ out,
                                                    int n8) {
  int i = blockIdx.x * 256 + threadIdx.x;
  if (i >= n8) return;
  const float4* p = reinterpret_cast<const float4*>(in) + (size_t)i * 2;
  float4 a = p[0], b = p[1];
  uint4 o;
  o.x = (unsigned)f2bf(a.x) | ((unsigned)f2bf(a.y) << 16);
  o.y = (unsigned)f2bf(a.z) | ((unsigned)f2bf(a.w) << 16);
  o.z = (unsigned)f2bf(b.x) | ((unsigned)f2bf(b.y) << 16);
  o.w = (unsigned)f2bf(b.z) | ((unsigned)f2bf(b.w) << 16);
  reinterpret_cast<uint4*>(out)[i] = o;
}

// ---------------- C = A[M,K] * B[N,K]^T, bf16 in, f32 acc ----------------
template <bool OUT_F32>
__global__ __launch_bounds__(256) void gemm_bt(const unsigned short* __restrict__ A,
                                               const unsigned short* __restrict__ B,
                                               void* __restrict__ Cv,
                                               int M, int N, int K) {
  __shared__ unsigned short As[128 * 32];
  __shared__ unsigned short Bs[128 * 32];
  const int tid = threadIdx.x;
  const int lane = tid & 63, wid = tid >> 6;
  const int g = lane >> 4, q = lane & 15;
  const int nbx = N >> 7;
  const int bx = blockIdx.x % nbx, by = blockIdx.x / nbx;
  const int tM = by << 7, tN = bx << 7;
  const int wm = (wid >> 1) * 64, wn = (wid & 1) * 64;

  f32x4 acc[4][4] = {};

  const int o0 = tid * 16;
  const int r0 = o0 >> 6, c0 = (o0 & 63) >> 1;
  const int r1 = r0 + 64;
  const unsigned short* gA0 = A + (size_t)(tM + r0) * K + c0;
  const unsigned short* gA1 = A + (size_t)(tM + r1) * K + c0;
  const unsigned short* gB0 = B + (size_t)(tN + r0) * K + c0;
  const unsigned short* gB1 = B + (size_t)(tN + r1) * K + c0;
  char* lA = (char*)As;
  char* lB = (char*)Bs;
  const int wo = wid * 1024;

  for (int kt = 0; kt < K; kt += 32) {
    gload16(gA0, lA + wo);
    gload16(gA1, lA + 4096 + wo);
    gload16(gB0, lB + wo);
    gload16(gB1, lB + 4096 + wo);
    gA0 += 32; gA1 += 32; gB0 += 32; gB1 += 32;
    __syncthreads();
    bf16x8 af[4], bfr[4];
#pragma unroll
    for (int i = 0; i < 4; ++i)
      af[i] = *(const bf16x8*)&As[(wm + i * 16 + q) * 32 + g * 8];
#pragma unroll
    for (int j = 0; j < 4; ++j)
      bfr[j] = *(const bf16x8*)&Bs[(wn + j * 16 + q) * 32 + g * 8];
#pragma unroll
    for (int i = 0; i < 4; ++i)
#pragma unroll
      for (int j = 0; j < 4; ++j)
        acc[i][j] = __builtin_amdgcn_mfma_f32_16x16x32_bf16(af[i], bfr[j], acc[i][j], 0, 0, 0);
    __syncthreads();
  }

  if constexpr (OUT_F32) {
    float* C = (float*)Cv;
#pragma unroll
    for (int i = 0; i < 4; ++i)
#pragma unroll
      for (int j = 0; j < 4; ++j)
#pragma unroll
        for (int r = 0; r < 4; ++r)
          C[(size_t)(tM + wm + i * 16 + g * 4 + r) * N + (tN + wn + j * 16 + q)] =
              acc[i][j][r];
  } else {
    unsigned short* C = (unsigned short*)Cv;
#pragma unroll
    for (int i = 0; i < 4; ++i)
#pragma unroll
      for (int j = 0; j < 4; ++j)
#pragma unroll
        for (int r = 0; r < 4; ++r)
          C[(size_t)(tM + wm + i * 16 + g * 4 + r) * N + (tN + wn + j * 16 + q)] =
              f2bf(acc[i][j][r]);
  }
}

// ---------------- causal flash attention ----------------
// Grid 512: blockIdx = bh*16 + pi; block handles q-tiles {31-pi, pi} (uniform
// 33 KV-iterations). 4 waves x 16 q-rows = 64-row q-tile, KVBLK=64.
// K staged to LDS via global_load_lds, double-buffered, XOR-swizzled
// (chunk16 ^= row&7 on both the pre-swizzled global source and the ds_read).
// V loads issued early (async-stage split), written transposed after barrier.
__global__ __launch_bounds__(256, 2) void mla_attn(const unsigned short* __restrict__ QP,
                                                   const unsigned short* __restrict__ KV,
                                                   unsigned short* __restrict__ AO) {
  __shared__ unsigned short Ks[2][64 * 128];  // 32 KiB, swizzled rows
  __shared__ unsigned short Vt[128 * 72];     // V^T [d][kv], stride 72
  __shared__ unsigned short Pl[4][16 * 72];   // per-wave P [q][kv]

  const int tid = threadIdx.x, lane = tid & 63, w = tid >> 6;
  const int g = lane >> 4, q = lane & 15;
  const int pi = blockIdx.x & 15;
  const int bh = blockIdx.x >> 4;
  const int h = bh & (NHEADS - 1), b = bh >> 4;

  const unsigned short* Qb = QP + (size_t)(b * SLEN) * 2048 + h * HDIM;
  const unsigned short* Kb = KV + (size_t)(b * SLEN) * 4096 + h * HDIM;
  const unsigned short* Vb = Kb + 2048;

  // K staging coords: thread covers rows srow+16i, chunk16 = sc16; swizzled src chunk
  const int srow = tid >> 4;
  const int sc16 = tid & 15;
  const int sc = sc16 ^ (srow & 7);
  const int q7 = (q & 7) << 4;  // read-side swizzle term (row&7 == q&7)

  const float sc_f = 0.08838834764831845f;  // 1/sqrt(128)

  for (int t2 = 0; t2 < 2; ++t2) {
    const int qt = t2 ? pi : 31 - pi;
    const int qrow0 = qt * 64;
    const int myq = qrow0 + w * 16 + q;

    bf16x8 qf[4];
#pragma unroll
    for (int c = 0; c < 4; ++c)
      qf[c] = *(const bf16x8*)(Qb + (size_t)myq * 2048 + c * 32 + g * 8);

    float m = -1e30f, l = 0.f;
    f32x4 o[8] = {};

    __syncthreads();  // protect LDS against previous tile's readers

    // prologue: stage K[0], issue V[0]
    {
      const unsigned short* src = Kb + (size_t)srow * 4096 + (sc << 3);
      char* dst = (char*)&Ks[0][0] + (w << 10);
      gload16(src, dst);
      gload16(src + 16 * 4096, dst + 4096);
      gload16(src + 32 * 4096, dst + 8192);
      gload16(src + 48 * 4096, dst + 12288);
    }
    bf16x8 vreg[4];
#pragma unroll
    for (int rr = 0; rr < 4; ++rr)
      vreg[rr] = *(const bf16x8*)(Vb + (size_t)lane * 4096 + w * 8 + rr * 32);

    for (int kt = 0; kt <= qt; ++kt) {
      const int cur = kt & 1;
      __syncthreads();  // K[kt] staged & visible; Vt free to overwrite

      // write V^T[kt] from regs (each wave owns disjoint d-chunks)
#pragma unroll
      for (int rr = 0; rr < 4; ++rr) {
        const int dc = w * 8 + rr * 32;
#pragma unroll
        for (int j = 0; j < 8; ++j)
          Vt[(dc + j) * 72 + lane] = (unsigned short)vreg[rr][j];
      }

      // prefetch K[kt+1] + V[kt+1] — latency hides under QK + softmax
      if (kt < qt) {
        const int kvn = (kt + 1) * 64;
        const unsigned short* src = Kb + (size_t)(kvn + srow) * 4096 + (sc << 3);
        char* dst = (char*)&Ks[cur ^ 1][0] + (w << 10);
        gload16(src, dst);
        gload16(src + 16 * 4096, dst + 4096);
        gload16(src + 32 * 4096, dst + 8192);
        gload16(src + 48 * 4096, dst + 12288);
#pragma unroll
        for (int rr = 0; rr < 4; ++rr)
          vreg[rr] = *(const bf16x8*)(Vb + (size_t)(kvn + lane) * 4096 + w * 8 + rr * 32);
      }

      // QK^T (swapped): S^T = K * Q^T, K A-frags from swizzled LDS
      f32x4 s4[4];
#pragma unroll
      for (int mf = 0; mf < 4; ++mf) {
        s4[mf] = (f32x4){0.f, 0.f, 0.f, 0.f};
        const char* kr = (const char*)&Ks[cur][(mf * 16 + q) * 128];
#pragma unroll
        for (int c = 0; c < 4; ++c) {
          bf16x8 af = *(const bf16x8*)(kr + ((((c << 2) | g) << 4) ^ q7));
          s4[mf] = __builtin_amdgcn_mfma_f32_16x16x32_bf16(af, qf[c], s4[mf], 0, 0, 0);
        }
      }

      // softmax (lane holds 16 scores of q-row myq)
      float p[16], tmax = -1e30f;
      if (kt == qt) {  // only the diagonal tile needs masking
        const int kvb = kt * 64;
#pragma unroll
        for (int mf = 0; mf < 4; ++mf)
#pragma unroll
          for (int r = 0; r < 4; ++r) {
            const int kv = kvb + mf * 16 + g * 4 + r;
            float s = (kv <= myq) ? s4[mf][r] * sc_f : -1e30f;
            p[mf * 4 + r] = s;
            tmax = fmaxf(tmax, s);
          }
      } else {
#pragma unroll
        for (int mf = 0; mf < 4; ++mf)
#pragma unroll
          for (int r = 0; r < 4; ++r) {
            float s = s4[mf][r] * sc_f;
            p[mf * 4 + r] = s;
            tmax = fmaxf(tmax, s);
          }
      }
      tmax = fmaxf(tmax, __shfl_xor(tmax, 16));
      tmax = fmaxf(tmax, __shfl_xor(tmax, 32));
      const float mnew = fmaxf(m, tmax);
      const float resc = __expf(m - mnew);
      m = mnew;
      float ts = 0.f;
#pragma unroll
      for (int i = 0; i < 16; ++i) { p[i] = __expf(p[i] - mnew); ts += p[i]; }
      ts += __shfl_xor(ts, 16);
      ts += __shfl_xor(ts, 32);
      l = l * resc + ts;

      float rs[4];
#pragma unroll
      for (int r = 0; r < 4; ++r) rs[r] = __shfl(resc, g * 4 + r);
#pragma unroll
      for (int nf = 0; nf < 8; ++nf)
#pragma unroll
        for (int r = 0; r < 4; ++r) o[nf][r] *= rs[r];

      // P -> LDS bf16 [q][kv]
      unsigned short* myP = &Pl[w][0];
#pragma unroll
      for (int mf = 0; mf < 4; ++mf) {
        unsigned lo = (unsigned)f2bf(p[mf * 4 + 0]) | ((unsigned)f2bf(p[mf * 4 + 1]) << 16);
        unsigned hi = (unsigned)f2bf(p[mf * 4 + 2]) | ((unsigned)f2bf(p[mf * 4 + 3]) << 16);
        *(uint2*)&myP[q * 72 + mf * 16 + g * 4] = make_uint2(lo, hi);
      }

      __syncthreads();  // Vt fully written (and K[kt+1]/V[kt+1] drained here)

      // PV: O[16q][128d] += P[16q][64kv] * V[64kv][128d]
#pragma unroll
      for (int t = 0; t < 2; ++t) {
        bf16x8 pa = *(const bf16x8*)&myP[q * 72 + t * 32 + g * 8];
#pragma unroll
        for (int nf = 0; nf < 8; ++nf) {
          bf16x8 vbf = *(const bf16x8*)&Vt[(nf * 16 + q) * 72 + t * 32 + g * 8];
          o[nf] = __builtin_amdgcn_mfma_f32_16x16x32_bf16(pa, vbf, o[nf], 0, 0, 0);
        }
      }
    }

    const float inv = 1.0f / l;
    float li[4];
#pragma unroll
    for (int r = 0; r < 4; ++r) li[r] = __shfl(inv, g * 4 + r);
    unsigned short* aop = AO + (size_t)(b * SLEN + qrow0 + w * 16) * 2048 + h * HDIM;
#pragma unroll
    for (int nf = 0; nf < 8; ++nf)
#pragma unroll
      for (int r = 0; r < 4; ++r)
        aop[(size_t)(g * 4 + r) * 2048 + nf * 16 + q] = f2bf(o[nf][r] * li[r]);
  }
}

extern "C" void kernel_launch(void* const* d_in, const int* in_sizes, int n_in,
                              void* d_out, int out_size, void* d_ws, size_t ws_size,
                              hipStream_t stream) {
  const float* q    = (const float*)d_in[0];
  const float* lat  = (const float*)d_in[1];
  const float* Wq   = (const float*)d_in[2];
  const float* Wkv  = (const float*)d_in[3];
  const float* Wout = (const float*)d_in[4];

  char* ws = (char*)d_ws;
  unsigned short* qbf   = (unsigned short*)(ws);
  unsigned short* aobf  = (unsigned short*)(ws);             // reuses qbf
  unsigned short* Wqbf  = (unsigned short*)(ws + 16777216);
  unsigned short* latbf = (unsigned short*)(ws + 25165824);
  unsigned short* Wkvbf = (unsigned short*)(ws + 29360128);
  unsigned short* Wobf  = (unsigned short*)(ws + 33554432);
  unsigned short* qpbf  = (unsigned short*)(ws + 41943040);
  unsigned short* kvbf  = (unsigned short*)(ws + 58720256);

  cvt_f32_bf16<<<4096, 256, 0, stream>>>(q, qbf, 1048576);
  cvt_f32_bf16<<<2048, 256, 0, stream>>>(Wq, Wqbf, 524288);
  cvt_f32_bf16<<<1024, 256, 0, stream>>>(lat, latbf, 262144);
  cvt_f32_bf16<<<1024, 256, 0, stream>>>(Wkv, Wkvbf, 262144);
  cvt_f32_bf16<<<2048, 256, 0, stream>>>(Wout, Wobf, 524288);

  gemm_bt<false><<<512, 256, 0, stream>>>(qbf, Wqbf, qpbf, 4096, 2048, 2048);
  gemm_bt<false><<<1024, 256, 0, stream>>>(latbf, Wkvbf, kvbf, 4096, 4096, 512);
  mla_attn<<<512, 256, 0, stream>>>(qpbf, kvbf, aobf);
  gemm_bt<true><<<512, 256, 0, stream>>>(aobf, Wobf, (float*)d_out, 4096, 2048, 2048);
}